// Round 15
// baseline (992.147 us; speedup 1.0000x reference)
//
#include <hip/hip_runtime.h>

#define DIV_UP(a,b) (((a)+(b)-1)/(b))

typedef float v4f __attribute__((ext_vector_type(4)));

// ---------- non-temporal helpers ----------
__device__ __forceinline__ float4 ntload4(const float* p) {
  v4f v = __builtin_nontemporal_load((const v4f*)p);
  return make_float4(v.x, v.y, v.z, v.w);
}

// ---------- ordered-uint float max keys ----------
__device__ __forceinline__ unsigned f2key(float f) {
  unsigned u = __float_as_uint(f);
  return (u & 0x80000000u) ? ~u : (u | 0x80000000u);
}
__device__ __forceinline__ float key2f(unsigned u) {
  unsigned b = (u & 0x80000000u) ? (u ^ 0x80000000u) : ~u;
  return __uint_as_float(b);
}

// ---------- bf16 pack/unpack (RNE) ----------
__device__ __forceinline__ unsigned short f2bf(float f) {
  unsigned u = __float_as_uint(f);
  unsigned r = u + 0x7FFFu + ((u >> 16) & 1u);
  return (unsigned short)(r >> 16);
}
__device__ __forceinline__ float bf2f(unsigned short s) {
  return __uint_as_float(((unsigned)s) << 16);
}

// ---------- utility ----------
__global__ void k_zero(int* p, int n) {
  int i = blockIdx.x * blockDim.x + threadIdx.x;
  if (i < n) p[i] = 0;
}

__global__ void k_dis(const int* __restrict__ cnt, float* __restrict__ dis, int N) {
  int i = blockIdx.x * blockDim.x + threadIdx.x;
  if (i < N) {
    int c = cnt[i];
    dis[i] = (c > 0) ? rsqrtf((float)c) : 0.0f;
  }
}

// ---------- 3-kernel exclusive scan over cnt -> rowptr ----------
__global__ void k_scan1(const int* __restrict__ cnt, int* __restrict__ incl,
                        int* __restrict__ bsum, int N) {
  __shared__ int s[1024];
  int t = threadIdx.x;
  int i = blockIdx.x * 1024 + t;
  int v = (i < N) ? cnt[i] : 0;
  s[t] = v;
  __syncthreads();
  for (int off = 1; off < 1024; off <<= 1) {
    int add = (t >= off) ? s[t - off] : 0;
    __syncthreads();
    s[t] += add;
    __syncthreads();
  }
  if (i < N) incl[i] = s[t];
  if (t == 1023) bsum[blockIdx.x] = s[1023];
}

__global__ void k_scan2(const int* __restrict__ bsum, int* __restrict__ bex, int nb) {
  if (threadIdx.x == 0) {
    int run = 0;
    for (int b = 0; b < nb; ++b) { bex[b] = run; run += bsum[b]; }
  }
}

__global__ void k_scan3(const int* __restrict__ incl, const int* __restrict__ cnt,
                        const int* __restrict__ bex, int* __restrict__ rowptr,
                        int* __restrict__ cursor, int N, int E) {
  int i = blockIdx.x * blockDim.x + threadIdx.x;
  if (i < N) {
    int v = incl[i] - cnt[i] + bex[i >> 10];
    rowptr[i] = v;
    cursor[i] = v;
  }
  if (i == 0) rowptr[N] = E;
}

// ---------- shortcut GEMM body: S = x @ W_sc + b_sc ----------
__device__ __forceinline__ void gemmsc_body(float* w_s, float* x_s, int bid,
                                            const float* __restrict__ X,
                                            const float* __restrict__ W,
                                            const float* __restrict__ bias,
                                            float* __restrict__ S, int N) {
  for (int i4 = threadIdx.x; i4 < 1024; i4 += 512)
    *(float4*)&w_s[i4 * 4] = ((const float4*)W)[i4];
  int rowbase = bid * 128;
  for (int i4 = threadIdx.x; i4 < 2048; i4 += 512) {
    int r = i4 >> 4, c4 = i4 & 15;
    int row = rowbase + r;
    float4 v = (row < N) ? ntload4(X + (size_t)row * 64 + c4 * 4)
                         : make_float4(0.f, 0.f, 0.f, 0.f);
    *(float4*)&x_s[r * 64 + c4 * 4] = v;
  }
  __syncthreads();

  int lane = threadIdx.x & 63;
  int wid = threadIdx.x >> 6;
  int r0 = wid * 16;
  float bv = bias[lane];
  float acc[16];
#pragma unroll
  for (int r = 0; r < 16; ++r) acc[r] = bv;

  for (int d4 = 0; d4 < 16; ++d4) {
    float w0 = w_s[(d4 * 4 + 0) * 64 + lane];
    float w1 = w_s[(d4 * 4 + 1) * 64 + lane];
    float w2 = w_s[(d4 * 4 + 2) * 64 + lane];
    float w3 = w_s[(d4 * 4 + 3) * 64 + lane];
#pragma unroll
    for (int r = 0; r < 16; ++r) {
      float4 xv = *(const float4*)&x_s[(r0 + r) * 64 + d4 * 4];
      float a = acc[r];
      a = fmaf(xv.x, w0, a);
      a = fmaf(xv.y, w1, a);
      a = fmaf(xv.z, w2, a);
      a = fmaf(xv.w, w3, a);
      acc[r] = a;
    }
  }

#pragma unroll
  for (int r = 0; r < 16; ++r) {
    int row = rowbase + r0 + r;
    if (row < N) __builtin_nontemporal_store(acc[r], &S[(size_t)row * 64 + lane]);
  }
}

// ---------- fused layer GEMM body ----------
// BNIN=false: input X fp32.  BNIN=true: input Xbf bf16; BN coefs computed
// in-block from sums/sumsq/g/be, + lrelu, applied during staging.
// Outputs: A02bf = bf16(X@W0+b - X@W2), Y1bf = bf16(X@W1), Y2bf = bf16(dis*X@W2)
template <bool BNIN>
__device__ __forceinline__ void gemm192_body(float* w_s, float* x_s, int bid,
                                             const float* __restrict__ X,
                                             const unsigned short* __restrict__ Xbf,
                                             const float* __restrict__ sums,
                                             const float* __restrict__ sumsq,
                                             const float* __restrict__ g,
                                             const float* __restrict__ be,
                                             const float* __restrict__ W,
                                             const float* __restrict__ bias,
                                             const float* __restrict__ dis,
                                             unsigned short* __restrict__ A02bf,
                                             unsigned short* __restrict__ Y1bf,
                                             unsigned short* __restrict__ Y2bf,
                                             int N) {
  __shared__ float sc_s[64], sh_s[64];
  if (BNIN) {
    if (threadIdx.x < 64) {
      int h = threadIdx.x;
      float inv_n = 1.0f / (float)N;
      float mu = sums[h] * inv_n;
      float var = sumsq[h] * inv_n - mu * mu;
      float sc = g[h] * rsqrtf(var + 1e-5f);
      sc_s[h] = sc;
      sh_s[h] = be[h] - mu * sc;
    }
    __syncthreads();
  }
  for (int i4 = threadIdx.x; i4 < 3072; i4 += 512) {
    int k = i4 >> 10, rem = i4 & 1023;
    int d = rem >> 4, h4 = rem & 15;
    float4 v = ((const float4*)W)[i4];
    *(float4*)&w_s[d * 192 + k * 64 + h4 * 4] = v;
  }
  int rowbase = bid * 128;
  for (int i4 = threadIdx.x; i4 < 2048; i4 += 512) {
    int r = i4 >> 4, c4 = i4 & 15;
    int row = rowbase + r;
    float4 v;
    if (BNIN) {
      if (row < N) {
        unsigned long long u = __builtin_nontemporal_load(
            (const unsigned long long*)(Xbf + (size_t)row * 64 + c4 * 4));
        v.x = bf2f((unsigned short)(u & 0xffffu));
        v.y = bf2f((unsigned short)((u >> 16) & 0xffffu));
        v.z = bf2f((unsigned short)((u >> 32) & 0xffffu));
        v.w = bf2f((unsigned short)(u >> 48));
      } else {
        v = make_float4(0.f, 0.f, 0.f, 0.f);
      }
      int cb = c4 * 4;
      float a = v.x * sc_s[cb + 0] + sh_s[cb + 0];
      float b = v.y * sc_s[cb + 1] + sh_s[cb + 1];
      float c = v.z * sc_s[cb + 2] + sh_s[cb + 2];
      float d = v.w * sc_s[cb + 3] + sh_s[cb + 3];
      v.x = (a > 0.f) ? a : 0.01f * a;
      v.y = (b > 0.f) ? b : 0.01f * b;
      v.z = (c > 0.f) ? c : 0.01f * c;
      v.w = (d > 0.f) ? d : 0.01f * d;
    } else {
      v = (row < N) ? ntload4(X + (size_t)row * 64 + c4 * 4)
                    : make_float4(0.f, 0.f, 0.f, 0.f);
    }
    *(float4*)&x_s[r * 64 + c4 * 4] = v;
  }
  __syncthreads();

  int lane = threadIdx.x & 63;
  int wid = threadIdx.x >> 6;
  int r0 = wid * 16;
  float bv = bias[lane];
  float acc[48];
#pragma unroll
  for (int r = 0; r < 16; ++r) {
    acc[r * 3 + 0] = bv;
    acc[r * 3 + 1] = 0.f;
    acc[r * 3 + 2] = 0.f;
  }

  for (int d4 = 0; d4 < 16; ++d4) {
    float w[12];
#pragma unroll
    for (int k = 0; k < 4; ++k)
#pragma unroll
      for (int j = 0; j < 3; ++j)
        w[k * 3 + j] = w_s[(d4 * 4 + k) * 192 + j * 64 + lane];
#pragma unroll
    for (int r = 0; r < 16; ++r) {
      float4 xv = *(const float4*)&x_s[(r0 + r) * 64 + d4 * 4];  // bcast
#pragma unroll
      for (int j = 0; j < 3; ++j) {
        float a = acc[r * 3 + j];
        a = fmaf(xv.x, w[0 * 3 + j], a);
        a = fmaf(xv.y, w[1 * 3 + j], a);
        a = fmaf(xv.z, w[2 * 3 + j], a);
        a = fmaf(xv.w, w[3 * 3 + j], a);
        acc[r * 3 + j] = a;
      }
    }
  }

#pragma unroll
  for (int r = 0; r < 16; ++r) {
    int row = rowbase + r0 + r;
    if (row < N) {
      size_t o = (size_t)row * 64 + lane;
      __builtin_nontemporal_store(f2bf(acc[r * 3 + 0] - acc[r * 3 + 2]), &A02bf[o]);
      __builtin_nontemporal_store(f2bf(acc[r * 3 + 1]), &Y1bf[o]);
      Y2bf[o] = f2bf(dis[row] * acc[r * 3 + 2]);  // gather source: keep cached
    }
  }
}

// ---------- fused A: [gemmsc | count | sentinel-zero] ----------
__global__ __launch_bounds__(512) void k_fused_a(const float* __restrict__ X,
                                                 const float* __restrict__ W,
                                                 const float* __restrict__ bias,
                                                 float* __restrict__ S,
                                                 const int* __restrict__ row,
                                                 int* __restrict__ cnt,
                                                 unsigned short* __restrict__ Y2bf,
                                                 unsigned short* __restrict__ Vbf,
                                                 int N, int E, int NBG, int NC) {
  __shared__ float w_s[64 * 64];
  __shared__ float x_s[128 * 64];
  int bid = blockIdx.x;
  if (bid < NBG) {
    gemmsc_body(w_s, x_s, bid, X, W, bias, S, N);
  } else if (bid < NBG + NC) {
    int e = (bid - NBG) * 512 + threadIdx.x;
    if (e < E) atomicAdd(&cnt[row[e]], 1);
  } else {
    if (threadIdx.x < 64) {
      Y2bf[(size_t)N * 64 + threadIdx.x] = 0;
      Vbf[(size_t)N * 64 + threadIdx.x] = 0;
    }
  }
}

// ---------- fused B: [gemm192(l0) | fill] ----------
__global__ __launch_bounds__(512) void k_fused_b(const float* __restrict__ X,
                                                 const float* __restrict__ W,
                                                 const float* __restrict__ bias,
                                                 const float* __restrict__ dis,
                                                 unsigned short* __restrict__ A02bf,
                                                 unsigned short* __restrict__ Y1bf,
                                                 unsigned short* __restrict__ Y2bf,
                                                 const int* __restrict__ row,
                                                 const int* __restrict__ col,
                                                 int* __restrict__ cursor,
                                                 int* __restrict__ ccol,
                                                 int N, int E, int NBG) {
  __shared__ float w_s[64 * 192];
  __shared__ float x_s[128 * 64];
  int bid = blockIdx.x;
  if (bid < NBG) {
    gemm192_body<false>(w_s, x_s, bid, X, nullptr, nullptr, nullptr, nullptr,
                        nullptr, W, bias, dis, A02bf, Y1bf, Y2bf, N);
  } else {
    int e = (bid - NBG) * 512 + threadIdx.x;
    if (e < E) {
      int r = row[e];
      int idx = atomicAdd(&cursor[r], 1);
      __builtin_nontemporal_store(col[e], &ccol[idx]);
    }
  }
}

// ---------- layer GEMM (l>=1, standalone; Cbf input + in-block BN) ----------
__global__ __launch_bounds__(512) void k_gemm192(const unsigned short* __restrict__ Cbf,
                                                 const float* __restrict__ sums,
                                                 const float* __restrict__ sumsq,
                                                 const float* __restrict__ g,
                                                 const float* __restrict__ be,
                                                 const float* __restrict__ W,
                                                 const float* __restrict__ bias,
                                                 const float* __restrict__ dis,
                                                 unsigned short* __restrict__ A02bf,
                                                 unsigned short* __restrict__ Y1bf,
                                                 unsigned short* __restrict__ Y2bf,
                                                 int N) {
  __shared__ float w_s[64 * 192];
  __shared__ float x_s[128 * 64];
  gemm192_body<true>(w_s, x_s, blockIdx.x, nullptr, Cbf, sums, sumsq, g, be,
                     W, bias, dis, A02bf, Y1bf, Y2bf, N);
}

// ---------- prop v8: dual-row x 16-deep gathers (raise MLP to ~27/wave) ------
// zbf PRE-SCALED: zbf[c] = bf16(dis[c]*z[c]);  (P z)[n] = -dis[n]*sum_c zbf[c]
// MODE 1: Vbf[n] = bf16( dis[n]*(bf2f(Y1bf[n]) - 2*dis[n]*acc) ); zeroes stats
// MODE 2: Cbf[n] = bf16( bf2f(A02bf[n]) - dis[n]*acc )  (+ fused BN stats fp32)
template <int MODE>
__global__ __launch_bounds__(256) void k_prop8(const int* __restrict__ rowptr,
                                               const int* __restrict__ ccol,
                                               const float* __restrict__ dis,
                                               const unsigned short* __restrict__ zbf,
                                               const unsigned short* __restrict__ inAbf,
                                               unsigned short* __restrict__ outbf,
                                               float* __restrict__ sums,
                                               float* __restrict__ sumsq,
                                               float* __restrict__ zstats,
                                               int N, int nwaves) {
  if (MODE == 1 && blockIdx.x == 0 && threadIdx.x < 128) zstats[threadIdx.x] = 0.f;
  int gw = blockIdx.x * 4 + (threadIdx.x >> 6);
  int lane = threadIdx.x & 63;
  int wid = threadIdx.x >> 6;
  float s_ = 0.f, s2_ = 0.f;

  for (int n = gw; n < N; n += 2 * nwaves) {
    int a = n;
    int b = n + nwaves;
    bool vb = b < N;
    int ja = rowptr[a], ea = rowptr[a + 1];
    int jb = vb ? rowptr[b] : 0;
    int eb = vb ? rowptr[b + 1] : 0;
    float acca = 0.f, accb = 0.f;
    while (ja < ea || jb < eb) {   // wave-uniform
      int ca[16], cb[16];
#pragma unroll
      for (int u = 0; u < 16; ++u) {
        int jja = ja + u, jjb = jb + u;
        int adra = (jja < ea) ? jja : 0;   // clamp OOB addresses
        int adrb = (jjb < eb) ? jjb : 0;
        int c1 = ccol[adra];
        int c2 = ccol[adrb];
        ca[u] = (jja < ea) ? c1 : N;       // row N is zeroed
        cb[u] = (jjb < eb) ? c2 : N;
      }
      float va[16], vbv[16];
#pragma unroll
      for (int u = 0; u < 16; ++u) {
        va[u] = bf2f(zbf[(size_t)ca[u] * 64 + lane]);
        vbv[u] = bf2f(zbf[(size_t)cb[u] * 64 + lane]);
      }
#pragma unroll
      for (int u = 0; u < 16; ++u) {
        acca += va[u];
        accb += vbv[u];
      }
      ja += 16;
      jb += 16;
    }
    // epilogue row a
    {
      float dn = dis[a];
      size_t o = (size_t)a * 64 + lane;
      float av = bf2f(__builtin_nontemporal_load(&inAbf[o]));
      if (MODE == 1) {
        float V = av - 2.f * dn * acca;
        outbf[o] = f2bf(dn * V);  // gather source for prop_b: keep cached
      } else {
        float v = av - dn * acca;
        __builtin_nontemporal_store(f2bf(v), &outbf[o]);
        s_ += v;
        s2_ = fmaf(v, v, s2_);
      }
    }
    // epilogue row b
    if (vb) {
      float dn = dis[b];
      size_t o = (size_t)b * 64 + lane;
      float av = bf2f(__builtin_nontemporal_load(&inAbf[o]));
      if (MODE == 1) {
        float V = av - 2.f * dn * accb;
        outbf[o] = f2bf(dn * V);
      } else {
        float v = av - dn * accb;
        __builtin_nontemporal_store(f2bf(v), &outbf[o]);
        s_ += v;
        s2_ = fmaf(v, v, s2_);
      }
    }
  }

  if (MODE == 2) {
    __shared__ float red[2][4][64];
    red[0][wid][lane] = s_;
    red[1][wid][lane] = s2_;
    __syncthreads();
    if (wid == 0) {
      float a = red[0][0][lane] + red[0][1][lane] + red[0][2][lane] + red[0][3][lane];
      float b = red[1][0][lane] + red[1][1][lane] + red[1][2][lane] + red[1][3][lane];
      atomicAdd(&sums[lane], a);
      atomicAdd(&sumsq[lane], b);
    }
  }
}

// ---------- pooling ----------
__global__ void k_poolinit(unsigned* __restrict__ pooled, int n) {
  int i = blockIdx.x * blockDim.x + threadIdx.x;
  if (i < n) pooled[i] = 0x007FFFFFu;  // key(-inf)
}

// fused: h = lrelu(bn(Cbf)) + S; segment-max into pooled (coefs in-block)
__global__ void k_bnpool(const unsigned short* __restrict__ Cbf,
                         const float* __restrict__ sums, const float* __restrict__ sumsq,
                         const float* __restrict__ g, const float* __restrict__ be,
                         const float* __restrict__ S, const int* __restrict__ batch,
                         unsigned* __restrict__ pooled, int N) {
  __shared__ float sc_s[64], sh_s[64];
  if (threadIdx.x < 64) {
    int h = threadIdx.x;
    float inv_n = 1.0f / (float)N;
    float mu = sums[h] * inv_n;
    float var = sumsq[h] * inv_n - mu * mu;
    float sc = g[h] * rsqrtf(var + 1e-5f);
    sc_s[h] = sc;
    sh_s[h] = be[h] - mu * sc;
  }
  __syncthreads();
  int t = threadIdx.x;
  int h = t & 63;
  int rsub = t >> 6;
  int base = blockIdx.x * 64;
  float sc = sc_s[h], sh = sh_s[h];
  int cur_g = -1;
  unsigned best = 0;
  for (int i = 0; i < 16; ++i) {
    int n = base + rsub + 4 * i;
    if (n >= N) break;
    int gidx = batch[n];
    size_t o = (size_t)n * 64 + h;
    float a = bf2f(__builtin_nontemporal_load(&Cbf[o])) * sc + sh;
    a = (a > 0.f) ? a : 0.01f * a;
    a += __builtin_nontemporal_load(&S[o]);
    unsigned k = f2key(a);
    if (gidx != cur_g) {
      if (cur_g >= 0) atomicMax(&pooled[cur_g * 64 + h], best);
      cur_g = gidx;
      best = k;
    } else {
      best = max(best, k);
    }
  }
  if (cur_g >= 0) atomicMax(&pooled[cur_g * 64 + h], best);
}

__global__ void k_final(const unsigned* __restrict__ pooled, const float* __restrict__ w_lin,
                        const float* __restrict__ b_lin, float* __restrict__ out) {
  int g = blockIdx.x;
  int h = threadIdx.x;
  float v = key2f(pooled[g * 64 + h]) * w_lin[h];
  for (int off = 32; off > 0; off >>= 1) v += __shfl_down(v, off, 64);
  if (h == 0) out[g] = v + b_lin[0];
}

extern "C" void kernel_launch(void* const* d_in, const int* in_sizes, int n_in,
                              void* d_out, int out_size, void* d_ws, size_t ws_size,
                              hipStream_t stream) {
  const float* x = (const float*)d_in[0];
  const int* ei = (const int*)d_in[1];
  const int* batch = (const int*)d_in[2];
  const float* w1 = (const float*)d_in[3];
  const float* b1 = (const float*)d_in[4];
  const float* w2 = (const float*)d_in[5];
  const float* b2 = (const float*)d_in[6];
  const float* w3 = (const float*)d_in[7];
  const float* b3 = (const float*)d_in[8];
  const float* g1 = (const float*)d_in[9];
  const float* be1 = (const float*)d_in[10];
  const float* g2 = (const float*)d_in[11];
  const float* be2 = (const float*)d_in[12];
  const float* g3 = (const float*)d_in[13];
  const float* be3 = (const float*)d_in[14];
  const float* w_sc = (const float*)d_in[15];
  const float* b_sc = (const float*)d_in[16];
  const float* w_lin = (const float*)d_in[17];
  const float* b_lin = (const float*)d_in[18];

  int N = in_sizes[0] / 64;
  int E = in_sizes[1] / 2;
  int G = out_size;
  const int* row = ei;
  const int* col = ei + E;

  char* p = (char*)d_ws;
  auto carve = [&](size_t bytes) -> void* {
    void* r = (void*)p;
    p += (bytes + 255) & ~(size_t)255;
    return r;
  };
  int* cnt = (int*)carve((size_t)N * 4);
  float* dis = (float*)carve((size_t)N * 4);
  int* rowptr = (int*)carve((size_t)(N + 1) * 4);
  int* cursor = (int*)carve((size_t)N * 4);
  int* incl = (int*)carve((size_t)N * 4);
  int* bsum = (int*)carve(1024);
  int* bex = (int*)carve(1024);
  int* ccol = (int*)carve((size_t)(E + 64) * 4);   // +64 pad
  float* S = (float*)carve((size_t)N * 64 * 4);
  unsigned short* A02bf = (unsigned short*)carve((size_t)N * 64 * 2);
  unsigned short* Y1bf = (unsigned short*)carve((size_t)N * 64 * 2);
  unsigned short* Y2bf = (unsigned short*)carve((size_t)(N + 1) * 64 * 2);  // row N = 0
  unsigned short* Vbf = (unsigned short*)carve((size_t)(N + 1) * 64 * 2);   // row N = 0
  unsigned short* Cbf = (unsigned short*)carve((size_t)N * 64 * 2);
  float* stats = (float*)carve(256 * 4);  // sums|sumsq
  unsigned* pooled = (unsigned*)carve((size_t)G * 64 * 4);

  int NBG = DIV_UP(N, 128);
  int NC = DIV_UP(E, 512);

  // ---- graph build + overlapped independent compute ----
  k_zero<<<DIV_UP(N, 256), 256, 0, stream>>>(cnt, N);
  // A: gemmsc || degree count || sentinel zero
  k_fused_a<<<NBG + NC + 1, 512, 0, stream>>>(x, w_sc, b_sc, S, row, cnt,
                                              Y2bf, Vbf, N, E, NBG, NC);
  k_dis<<<DIV_UP(N, 256), 256, 0, stream>>>(cnt, dis, N);
  int nb = DIV_UP(N, 1024);
  k_scan1<<<nb, 1024, 0, stream>>>(cnt, incl, bsum, N);
  k_scan2<<<1, 64, 0, stream>>>(bsum, bex, nb);
  k_scan3<<<DIV_UP(N, 256), 256, 0, stream>>>(incl, cnt, bex, rowptr, cursor, N, E);
  // B: gemm192(layer0) || CSR fill
  k_fused_b<<<NBG + NC, 512, 0, stream>>>(x, w1, b1, dis, A02bf, Y1bf, Y2bf,
                                          row, col, cursor, ccol, N, E, NBG);

  const float* Ws[3] = {w1, w2, w3};
  const float* bs[3] = {b1, b2, b3};
  const float* gs[3] = {g1, g2, g3};
  const float* bes[3] = {be1, be2, be3};

  const int PBLK = 2048;      // persistent blocks, 4 waves each
  const int NWAVE = PBLK * 4;
  for (int l = 0; l < 3; ++l) {
    if (l > 0)
      k_gemm192<<<NBG, 512, 0, stream>>>(Cbf, stats, stats + 64, gs[l - 1], bes[l - 1],
                                         Ws[l], bs[l], dis, A02bf, Y1bf, Y2bf, N);
    // Vbf = bf16( dis * (Y1 + 2*P*Y2) )   (also zeroes stats)
    k_prop8<1><<<PBLK, 256, 0, stream>>>(rowptr, ccol, dis, Y2bf, Y1bf,
                                         Vbf, nullptr, nullptr, stats, N, NWAVE);
    // Cbf = bf16( (Y0 - Y2) + P*V )  (+ fused BN stats)
    k_prop8<2><<<PBLK, 256, 0, stream>>>(rowptr, ccol, dis, Vbf, A02bf,
                                         Cbf, stats, stats + 64, nullptr, N, NWAVE);
  }

  k_poolinit<<<DIV_UP(G * 64, 256), 256, 0, stream>>>(pooled, G * 64);
  k_bnpool<<<DIV_UP(N, 64), 256, 0, stream>>>(Cbf, stats, stats + 64, g3, be3,
                                              S, batch, pooled, N);
  k_final<<<G, 64, 0, stream>>>(pooled, w_lin, b_lin, (float*)d_out);
}

// Round 16
// 883.887 us; speedup vs baseline: 1.1225x; 1.1225x over previous
//
#include <hip/hip_runtime.h>

#define DIV_UP(a,b) (((a)+(b)-1)/(b))

typedef float v4f __attribute__((ext_vector_type(4)));

// ---------- non-temporal helpers ----------
__device__ __forceinline__ float4 ntload4(const float* p) {
  v4f v = __builtin_nontemporal_load((const v4f*)p);
  return make_float4(v.x, v.y, v.z, v.w);
}

// ---------- ordered-uint float max keys ----------
__device__ __forceinline__ unsigned f2key(float f) {
  unsigned u = __float_as_uint(f);
  return (u & 0x80000000u) ? ~u : (u | 0x80000000u);
}
__device__ __forceinline__ float key2f(unsigned u) {
  unsigned b = (u & 0x80000000u) ? (u ^ 0x80000000u) : ~u;
  return __uint_as_float(b);
}

// ---------- bf16 pack/unpack (RNE) ----------
__device__ __forceinline__ unsigned short f2bf(float f) {
  unsigned u = __float_as_uint(f);
  unsigned r = u + 0x7FFFu + ((u >> 16) & 1u);
  return (unsigned short)(r >> 16);
}
__device__ __forceinline__ float bf2f(unsigned short s) {
  return __uint_as_float(((unsigned)s) << 16);
}

// ---------- utility ----------
__global__ void k_zero(int* p, int n) {
  int i = blockIdx.x * blockDim.x + threadIdx.x;
  if (i < n) p[i] = 0;
}

__global__ void k_dis(const int* __restrict__ cnt, float* __restrict__ dis, int N) {
  int i = blockIdx.x * blockDim.x + threadIdx.x;
  if (i < N) {
    int c = cnt[i];
    dis[i] = (c > 0) ? rsqrtf((float)c) : 0.0f;
  }
}

// ---------- 3-kernel exclusive scan over cnt -> rowptr ----------
__global__ void k_scan1(const int* __restrict__ cnt, int* __restrict__ incl,
                        int* __restrict__ bsum, int N) {
  __shared__ int s[1024];
  int t = threadIdx.x;
  int i = blockIdx.x * 1024 + t;
  int v = (i < N) ? cnt[i] : 0;
  s[t] = v;
  __syncthreads();
  for (int off = 1; off < 1024; off <<= 1) {
    int add = (t >= off) ? s[t - off] : 0;
    __syncthreads();
    s[t] += add;
    __syncthreads();
  }
  if (i < N) incl[i] = s[t];
  if (t == 1023) bsum[blockIdx.x] = s[1023];
}

__global__ void k_scan2(const int* __restrict__ bsum, int* __restrict__ bex, int nb) {
  if (threadIdx.x == 0) {
    int run = 0;
    for (int b = 0; b < nb; ++b) { bex[b] = run; run += bsum[b]; }
  }
}

__global__ void k_scan3(const int* __restrict__ incl, const int* __restrict__ cnt,
                        const int* __restrict__ bex, int* __restrict__ rowptr,
                        int* __restrict__ cursor, int N, int E) {
  int i = blockIdx.x * blockDim.x + threadIdx.x;
  if (i < N) {
    int v = incl[i] - cnt[i] + bex[i >> 10];
    rowptr[i] = v;
    cursor[i] = v;
  }
  if (i == 0) rowptr[N] = E;
}

// ---------- shortcut GEMM body: Sbf = bf16(x @ W_sc + b_sc) ----------
__device__ __forceinline__ void gemmsc_body(float* w_s, float* x_s, int bid,
                                            const float* __restrict__ X,
                                            const float* __restrict__ W,
                                            const float* __restrict__ bias,
                                            unsigned short* __restrict__ Sbf, int N) {
  for (int i4 = threadIdx.x; i4 < 1024; i4 += 512)
    *(float4*)&w_s[i4 * 4] = ((const float4*)W)[i4];
  int rowbase = bid * 128;
  for (int i4 = threadIdx.x; i4 < 2048; i4 += 512) {
    int r = i4 >> 4, c4 = i4 & 15;
    int row = rowbase + r;
    float4 v = (row < N) ? ntload4(X + (size_t)row * 64 + c4 * 4)
                         : make_float4(0.f, 0.f, 0.f, 0.f);
    *(float4*)&x_s[r * 64 + c4 * 4] = v;
  }
  __syncthreads();

  int lane = threadIdx.x & 63;
  int wid = threadIdx.x >> 6;
  int r0 = wid * 16;
  float bv = bias[lane];
  float acc[16];
#pragma unroll
  for (int r = 0; r < 16; ++r) acc[r] = bv;

  for (int d4 = 0; d4 < 16; ++d4) {
    float w0 = w_s[(d4 * 4 + 0) * 64 + lane];
    float w1 = w_s[(d4 * 4 + 1) * 64 + lane];
    float w2 = w_s[(d4 * 4 + 2) * 64 + lane];
    float w3 = w_s[(d4 * 4 + 3) * 64 + lane];
#pragma unroll
    for (int r = 0; r < 16; ++r) {
      float4 xv = *(const float4*)&x_s[(r0 + r) * 64 + d4 * 4];
      float a = acc[r];
      a = fmaf(xv.x, w0, a);
      a = fmaf(xv.y, w1, a);
      a = fmaf(xv.z, w2, a);
      a = fmaf(xv.w, w3, a);
      acc[r] = a;
    }
  }

#pragma unroll
  for (int r = 0; r < 16; ++r) {
    int row = rowbase + r0 + r;
    if (row < N)
      __builtin_nontemporal_store(f2bf(acc[r]), &Sbf[(size_t)row * 64 + lane]);
  }
}

// ---------- fused layer GEMM body ----------
// BNIN=false: input X fp32.  BNIN=true: input Xbf bf16; BN coefs computed
// in-block from sums/sumsq/g/be, + lrelu, applied during staging.
// Outputs: A02bf = bf16(X@W0+b - X@W2), Y1bf = bf16(X@W1), Y2bf = bf16(dis*X@W2)
template <bool BNIN>
__device__ __forceinline__ void gemm192_body(float* w_s, float* x_s, int bid,
                                             const float* __restrict__ X,
                                             const unsigned short* __restrict__ Xbf,
                                             const float* __restrict__ sums,
                                             const float* __restrict__ sumsq,
                                             const float* __restrict__ g,
                                             const float* __restrict__ be,
                                             const float* __restrict__ W,
                                             const float* __restrict__ bias,
                                             const float* __restrict__ dis,
                                             unsigned short* __restrict__ A02bf,
                                             unsigned short* __restrict__ Y1bf,
                                             unsigned short* __restrict__ Y2bf,
                                             int N) {
  __shared__ float sc_s[64], sh_s[64];
  if (BNIN) {
    if (threadIdx.x < 64) {
      int h = threadIdx.x;
      float inv_n = 1.0f / (float)N;
      float mu = sums[h] * inv_n;
      float var = sumsq[h] * inv_n - mu * mu;
      float sc = g[h] * rsqrtf(var + 1e-5f);
      sc_s[h] = sc;
      sh_s[h] = be[h] - mu * sc;
    }
    __syncthreads();
  }
  for (int i4 = threadIdx.x; i4 < 3072; i4 += 512) {
    int k = i4 >> 10, rem = i4 & 1023;
    int d = rem >> 4, h4 = rem & 15;
    float4 v = ((const float4*)W)[i4];
    *(float4*)&w_s[d * 192 + k * 64 + h4 * 4] = v;
  }
  int rowbase = bid * 128;
  for (int i4 = threadIdx.x; i4 < 2048; i4 += 512) {
    int r = i4 >> 4, c4 = i4 & 15;
    int row = rowbase + r;
    float4 v;
    if (BNIN) {
      if (row < N) {
        unsigned long long u = __builtin_nontemporal_load(
            (const unsigned long long*)(Xbf + (size_t)row * 64 + c4 * 4));
        v.x = bf2f((unsigned short)(u & 0xffffu));
        v.y = bf2f((unsigned short)((u >> 16) & 0xffffu));
        v.z = bf2f((unsigned short)((u >> 32) & 0xffffu));
        v.w = bf2f((unsigned short)(u >> 48));
      } else {
        v = make_float4(0.f, 0.f, 0.f, 0.f);
      }
      int cb = c4 * 4;
      float a = v.x * sc_s[cb + 0] + sh_s[cb + 0];
      float b = v.y * sc_s[cb + 1] + sh_s[cb + 1];
      float c = v.z * sc_s[cb + 2] + sh_s[cb + 2];
      float d = v.w * sc_s[cb + 3] + sh_s[cb + 3];
      v.x = (a > 0.f) ? a : 0.01f * a;
      v.y = (b > 0.f) ? b : 0.01f * b;
      v.z = (c > 0.f) ? c : 0.01f * c;
      v.w = (d > 0.f) ? d : 0.01f * d;
    } else {
      v = (row < N) ? ntload4(X + (size_t)row * 64 + c4 * 4)
                    : make_float4(0.f, 0.f, 0.f, 0.f);
    }
    *(float4*)&x_s[r * 64 + c4 * 4] = v;
  }
  __syncthreads();

  int lane = threadIdx.x & 63;
  int wid = threadIdx.x >> 6;
  int r0 = wid * 16;
  float bv = bias[lane];
  float acc[48];
#pragma unroll
  for (int r = 0; r < 16; ++r) {
    acc[r * 3 + 0] = bv;
    acc[r * 3 + 1] = 0.f;
    acc[r * 3 + 2] = 0.f;
  }

  for (int d4 = 0; d4 < 16; ++d4) {
    float w[12];
#pragma unroll
    for (int k = 0; k < 4; ++k)
#pragma unroll
      for (int j = 0; j < 3; ++j)
        w[k * 3 + j] = w_s[(d4 * 4 + k) * 192 + j * 64 + lane];
#pragma unroll
    for (int r = 0; r < 16; ++r) {
      float4 xv = *(const float4*)&x_s[(r0 + r) * 64 + d4 * 4];  // bcast
#pragma unroll
      for (int j = 0; j < 3; ++j) {
        float a = acc[r * 3 + j];
        a = fmaf(xv.x, w[0 * 3 + j], a);
        a = fmaf(xv.y, w[1 * 3 + j], a);
        a = fmaf(xv.z, w[2 * 3 + j], a);
        a = fmaf(xv.w, w[3 * 3 + j], a);
        acc[r * 3 + j] = a;
      }
    }
  }

#pragma unroll
  for (int r = 0; r < 16; ++r) {
    int row = rowbase + r0 + r;
    if (row < N) {
      size_t o = (size_t)row * 64 + lane;
      __builtin_nontemporal_store(f2bf(acc[r * 3 + 0] - acc[r * 3 + 2]), &A02bf[o]);
      __builtin_nontemporal_store(f2bf(acc[r * 3 + 1]), &Y1bf[o]);
      Y2bf[o] = f2bf(dis[row] * acc[r * 3 + 2]);  // gather source: keep cached
    }
  }
}

// ---------- fused A (role-interleaved): gemmsc | count | sentinel ----------
__global__ __launch_bounds__(512) void k_fused_a(const float* __restrict__ X,
                                                 const float* __restrict__ W,
                                                 const float* __restrict__ bias,
                                                 unsigned short* __restrict__ Sbf,
                                                 const int* __restrict__ row,
                                                 int* __restrict__ cnt,
                                                 unsigned short* __restrict__ Y2bf,
                                                 unsigned short* __restrict__ Vbf,
                                                 int N, int E, int NBG, int NC, int q) {
  __shared__ float w_s[64 * 64];
  __shared__ float x_s[128 * 64];
  int bid = blockIdx.x;
  bool isg = (bid % q == 0) && (bid / q < NBG);
  if (isg) {
    gemmsc_body(w_s, x_s, bid / q, X, W, bias, Sbf, N);
  } else {
    int before = min((bid + q - 1) / q, NBG);
    int oi = bid - before;
    if (oi < NC) {
      int e = oi * 512 + threadIdx.x;
      if (e < E) atomicAdd(&cnt[row[e]], 1);
    } else {
      if (threadIdx.x < 64) {
        Y2bf[(size_t)N * 64 + threadIdx.x] = 0;
        Vbf[(size_t)N * 64 + threadIdx.x] = 0;
      }
    }
  }
}

// ---------- fused B (role-interleaved): gemm192(l0) | fill ----------
__global__ __launch_bounds__(512) void k_fused_b(const float* __restrict__ X,
                                                 const float* __restrict__ W,
                                                 const float* __restrict__ bias,
                                                 const float* __restrict__ dis,
                                                 unsigned short* __restrict__ A02bf,
                                                 unsigned short* __restrict__ Y1bf,
                                                 unsigned short* __restrict__ Y2bf,
                                                 const int* __restrict__ row,
                                                 const int* __restrict__ col,
                                                 int* __restrict__ cursor,
                                                 int* __restrict__ ccol,
                                                 int N, int E, int NBG, int q) {
  __shared__ float w_s[64 * 192];
  __shared__ float x_s[128 * 64];
  int bid = blockIdx.x;
  bool isg = (bid % q == 0) && (bid / q < NBG);
  if (isg) {
    gemm192_body<false>(w_s, x_s, bid / q, X, nullptr, nullptr, nullptr, nullptr,
                        nullptr, W, bias, dis, A02bf, Y1bf, Y2bf, N);
  } else {
    int before = min((bid + q - 1) / q, NBG);
    int oi = bid - before;
    int e = oi * 512 + threadIdx.x;
    if (e < E) {
      int r = row[e];
      int idx = atomicAdd(&cursor[r], 1);
      __builtin_nontemporal_store(col[e], &ccol[idx]);
    }
  }
}

// ---------- layer GEMM (l>=1, standalone; Cbf input + in-block BN) ----------
__global__ __launch_bounds__(512) void k_gemm192(const unsigned short* __restrict__ Cbf,
                                                 const float* __restrict__ sums,
                                                 const float* __restrict__ sumsq,
                                                 const float* __restrict__ g,
                                                 const float* __restrict__ be,
                                                 const float* __restrict__ W,
                                                 const float* __restrict__ bias,
                                                 const float* __restrict__ dis,
                                                 unsigned short* __restrict__ A02bf,
                                                 unsigned short* __restrict__ Y1bf,
                                                 unsigned short* __restrict__ Y2bf,
                                                 int N) {
  __shared__ float w_s[64 * 192];
  __shared__ float x_s[128 * 64];
  gemm192_body<true>(w_s, x_s, blockIdx.x, nullptr, Cbf, sums, sumsq, g, be,
                     W, bias, dis, A02bf, Y1bf, Y2bf, N);
}

// ---------- prop v4 (R12 structure): row-per-wave persistent, 16-deep -------
// zbf PRE-SCALED: zbf[c] = bf16(dis[c]*z[c]);  (P z)[n] = -dis[n]*sum_c zbf[c]
// MODE 1: Vbf[n] = bf16( dis[n]*(bf2f(Y1bf[n]) - 2*dis[n]*acc) ); zeroes stats
// MODE 2: Cbf[n] = bf16( bf2f(A02bf[n]) - dis[n]*acc )  (+ fused BN stats fp32)
template <int MODE>
__global__ __launch_bounds__(256) void k_prop4(const int* __restrict__ rowptr,
                                               const int* __restrict__ ccol,
                                               const float* __restrict__ dis,
                                               const unsigned short* __restrict__ zbf,
                                               const unsigned short* __restrict__ inAbf,
                                               unsigned short* __restrict__ outbf,
                                               float* __restrict__ sums,
                                               float* __restrict__ sumsq,
                                               float* __restrict__ zstats,
                                               int N, int nwaves) {
  if (MODE == 1 && blockIdx.x == 0 && threadIdx.x < 128) zstats[threadIdx.x] = 0.f;
  int gw = blockIdx.x * 4 + (threadIdx.x >> 6);
  int lane = threadIdx.x & 63;
  int wid = threadIdx.x >> 6;
  float s_ = 0.f, s2_ = 0.f;
  for (int n = gw; n < N; n += nwaves) {
    int beg = rowptr[n], end = rowptr[n + 1];
    float acc = 0.f;
    for (int j = beg; j < end; j += 16) {
      int cc[16];
#pragma unroll
      for (int u = 0; u < 16; ++u) {
        int jj = j + u;
        int c = ccol[jj];            // allocation padded by 16 -> safe load
        cc[u] = (jj < end) ? c : N;  // row N is zeroed
      }
      float vv[16];
#pragma unroll
      for (int u = 0; u < 16; ++u) vv[u] = bf2f(zbf[(size_t)cc[u] * 64 + lane]);
#pragma unroll
      for (int u = 0; u < 16; ++u) acc += vv[u];
    }
    float dn = dis[n];
    size_t o = (size_t)n * 64 + lane;
    float av = bf2f(__builtin_nontemporal_load(&inAbf[o]));
    if (MODE == 1) {
      float V = av - 2.f * dn * acc;
      outbf[o] = f2bf(dn * V);  // gather source for prop_b: keep cached
    } else {
      float v = av - dn * acc;
      __builtin_nontemporal_store(f2bf(v), &outbf[o]);
      s_ += v;
      s2_ = fmaf(v, v, s2_);
    }
  }
  if (MODE == 2) {
    __shared__ float red[2][4][64];
    red[0][wid][lane] = s_;
    red[1][wid][lane] = s2_;
    __syncthreads();
    if (wid == 0) {
      float a = red[0][0][lane] + red[0][1][lane] + red[0][2][lane] + red[0][3][lane];
      float b = red[1][0][lane] + red[1][1][lane] + red[1][2][lane] + red[1][3][lane];
      atomicAdd(&sums[lane], a);
      atomicAdd(&sumsq[lane], b);
    }
  }
}

// ---------- pooling ----------
__global__ void k_poolinit(unsigned* __restrict__ pooled, int n) {
  int i = blockIdx.x * blockDim.x + threadIdx.x;
  if (i < n) pooled[i] = 0x007FFFFFu;  // key(-inf)
}

// fused: h = lrelu(bn(Cbf)) + Sbf; segment-max into pooled (coefs in-block)
__global__ void k_bnpool(const unsigned short* __restrict__ Cbf,
                         const float* __restrict__ sums, const float* __restrict__ sumsq,
                         const float* __restrict__ g, const float* __restrict__ be,
                         const unsigned short* __restrict__ Sbf,
                         const int* __restrict__ batch,
                         unsigned* __restrict__ pooled, int N) {
  __shared__ float sc_s[64], sh_s[64];
  if (threadIdx.x < 64) {
    int h = threadIdx.x;
    float inv_n = 1.0f / (float)N;
    float mu = sums[h] * inv_n;
    float var = sumsq[h] * inv_n - mu * mu;
    float sc = g[h] * rsqrtf(var + 1e-5f);
    sc_s[h] = sc;
    sh_s[h] = be[h] - mu * sc;
  }
  __syncthreads();
  int t = threadIdx.x;
  int h = t & 63;
  int rsub = t >> 6;
  int base = blockIdx.x * 64;
  float sc = sc_s[h], sh = sh_s[h];
  int cur_g = -1;
  unsigned best = 0;
  for (int i = 0; i < 16; ++i) {
    int n = base + rsub + 4 * i;
    if (n >= N) break;
    int gidx = batch[n];
    size_t o = (size_t)n * 64 + h;
    float a = bf2f(__builtin_nontemporal_load(&Cbf[o])) * sc + sh;
    a = (a > 0.f) ? a : 0.01f * a;
    a += bf2f(__builtin_nontemporal_load(&Sbf[o]));
    unsigned k = f2key(a);
    if (gidx != cur_g) {
      if (cur_g >= 0) atomicMax(&pooled[cur_g * 64 + h], best);
      cur_g = gidx;
      best = k;
    } else {
      best = max(best, k);
    }
  }
  if (cur_g >= 0) atomicMax(&pooled[cur_g * 64 + h], best);
}

__global__ void k_final(const unsigned* __restrict__ pooled, const float* __restrict__ w_lin,
                        const float* __restrict__ b_lin, float* __restrict__ out) {
  int g = blockIdx.x;
  int h = threadIdx.x;
  float v = key2f(pooled[g * 64 + h]) * w_lin[h];
  for (int off = 32; off > 0; off >>= 1) v += __shfl_down(v, off, 64);
  if (h == 0) out[g] = v + b_lin[0];
}

extern "C" void kernel_launch(void* const* d_in, const int* in_sizes, int n_in,
                              void* d_out, int out_size, void* d_ws, size_t ws_size,
                              hipStream_t stream) {
  const float* x = (const float*)d_in[0];
  const int* ei = (const int*)d_in[1];
  const int* batch = (const int*)d_in[2];
  const float* w1 = (const float*)d_in[3];
  const float* b1 = (const float*)d_in[4];
  const float* w2 = (const float*)d_in[5];
  const float* b2 = (const float*)d_in[6];
  const float* w3 = (const float*)d_in[7];
  const float* b3 = (const float*)d_in[8];
  const float* g1 = (const float*)d_in[9];
  const float* be1 = (const float*)d_in[10];
  const float* g2 = (const float*)d_in[11];
  const float* be2 = (const float*)d_in[12];
  const float* g3 = (const float*)d_in[13];
  const float* be3 = (const float*)d_in[14];
  const float* w_sc = (const float*)d_in[15];
  const float* b_sc = (const float*)d_in[16];
  const float* w_lin = (const float*)d_in[17];
  const float* b_lin = (const float*)d_in[18];

  int N = in_sizes[0] / 64;
  int E = in_sizes[1] / 2;
  int G = out_size;
  const int* row = ei;
  const int* col = ei + E;

  char* p = (char*)d_ws;
  auto carve = [&](size_t bytes) -> void* {
    void* r = (void*)p;
    p += (bytes + 255) & ~(size_t)255;
    return r;
  };
  int* cnt = (int*)carve((size_t)N * 4);
  float* dis = (float*)carve((size_t)N * 4);
  int* rowptr = (int*)carve((size_t)(N + 1) * 4);
  int* cursor = (int*)carve((size_t)N * 4);
  int* incl = (int*)carve((size_t)N * 4);
  int* bsum = (int*)carve(1024);
  int* bex = (int*)carve(1024);
  int* ccol = (int*)carve((size_t)(E + 64) * 4);   // +64 pad for batch over-read
  unsigned short* Sbf = (unsigned short*)carve((size_t)N * 64 * 2);
  unsigned short* A02bf = (unsigned short*)carve((size_t)N * 64 * 2);
  unsigned short* Y1bf = (unsigned short*)carve((size_t)N * 64 * 2);
  unsigned short* Y2bf = (unsigned short*)carve((size_t)(N + 1) * 64 * 2);  // row N = 0
  unsigned short* Vbf = (unsigned short*)carve((size_t)(N + 1) * 64 * 2);   // row N = 0
  unsigned short* Cbf = (unsigned short*)carve((size_t)N * 64 * 2);
  float* stats = (float*)carve(256 * 4);  // sums|sumsq
  unsigned* pooled = (unsigned*)carve((size_t)G * 64 * 4);

  int NBG = DIV_UP(N, 128);
  int NC = DIV_UP(E, 512);
  // role-interleave stride: gemm blocks at bid % q == 0
  int TA = NBG + NC + 1;
  int qa = (NBG > 1) ? (TA - 1) / (NBG - 1) : 1;
  if (qa < 1) qa = 1;
  int TB = NBG + NC;
  int qb = (NBG > 1) ? (TB - 1) / (NBG - 1) : 1;
  if (qb < 1) qb = 1;

  // ---- graph build + overlapped independent compute ----
  k_zero<<<DIV_UP(N, 256), 256, 0, stream>>>(cnt, N);
  // A: gemmsc || degree count || sentinel zero   (role-interleaved)
  k_fused_a<<<TA, 512, 0, stream>>>(x, w_sc, b_sc, Sbf, row, cnt,
                                    Y2bf, Vbf, N, E, NBG, NC, qa);
  k_dis<<<DIV_UP(N, 256), 256, 0, stream>>>(cnt, dis, N);
  int nb = DIV_UP(N, 1024);
  k_scan1<<<nb, 1024, 0, stream>>>(cnt, incl, bsum, N);
  k_scan2<<<1, 64, 0, stream>>>(bsum, bex, nb);
  k_scan3<<<DIV_UP(N, 256), 256, 0, stream>>>(incl, cnt, bex, rowptr, cursor, N, E);
  // B: gemm192(layer0) || CSR fill   (role-interleaved)
  k_fused_b<<<TB, 512, 0, stream>>>(x, w1, b1, dis, A02bf, Y1bf, Y2bf,
                                    row, col, cursor, ccol, N, E, NBG, qb);

  const float* Ws[3] = {w1, w2, w3};
  const float* bs[3] = {b1, b2, b3};
  const float* gs[3] = {g1, g2, g3};
  const float* bes[3] = {be1, be2, be3};

  const int PBLK = 2048;      // persistent blocks, 4 waves each
  const int NWAVE = PBLK * 4;
  for (int l = 0; l < 3; ++l) {
    if (l > 0)
      k_gemm192<<<NBG, 512, 0, stream>>>(Cbf, stats, stats + 64, gs[l - 1], bes[l - 1],
                                         Ws[l], bs[l], dis, A02bf, Y1bf, Y2bf, N);
    // Vbf = bf16( dis * (Y1 + 2*P*Y2) )   (also zeroes stats)
    k_prop4<1><<<PBLK, 256, 0, stream>>>(rowptr, ccol, dis, Y2bf, Y1bf,
                                         Vbf, nullptr, nullptr, stats, N, NWAVE);
    // Cbf = bf16( (Y0 - Y2) + P*V )  (+ fused BN stats)
    k_prop4<2><<<PBLK, 256, 0, stream>>>(rowptr, ccol, dis, Vbf, A02bf,
                                         Cbf, stats, stats + 64, nullptr, N, NWAVE);
  }

  k_poolinit<<<DIV_UP(G * 64, 256), 256, 0, stream>>>(pooled, G * 64);
  k_bnpool<<<DIV_UP(N, 64), 256, 0, stream>>>(Cbf, stats, stats + 64, g3, be3,
                                              Sbf, batch, pooled, N);
  k_final<<<G, 64, 0, stream>>>(pooled, w_lin, b_lin, (float*)d_out);
}

// Round 17
// 871.622 us; speedup vs baseline: 1.1383x; 1.0141x over previous
//
#include <hip/hip_runtime.h>

#define DIV_UP(a,b) (((a)+(b)-1)/(b))

typedef float v4f __attribute__((ext_vector_type(4)));

// ---------- non-temporal helpers ----------
__device__ __forceinline__ float4 ntload4(const float* p) {
  v4f v = __builtin_nontemporal_load((const v4f*)p);
  return make_float4(v.x, v.y, v.z, v.w);
}

// ---------- ordered-uint float max keys ----------
__device__ __forceinline__ unsigned f2key(float f) {
  unsigned u = __float_as_uint(f);
  return (u & 0x80000000u) ? ~u : (u | 0x80000000u);
}
__device__ __forceinline__ float key2f(unsigned u) {
  unsigned b = (u & 0x80000000u) ? (u ^ 0x80000000u) : ~u;
  return __uint_as_float(b);
}

// ---------- bf16 pack/unpack (RNE) ----------
__device__ __forceinline__ unsigned short f2bf(float f) {
  unsigned u = __float_as_uint(f);
  unsigned r = u + 0x7FFFu + ((u >> 16) & 1u);
  return (unsigned short)(r >> 16);
}
__device__ __forceinline__ float bf2f(unsigned short s) {
  return __uint_as_float(((unsigned)s) << 16);
}

// ---------- 3-kernel exclusive scan over cnt -> rowptr (+ dis in scan3) -----
__global__ void k_scan1(const int* __restrict__ cnt, int* __restrict__ incl,
                        int* __restrict__ bsum, int N) {
  __shared__ int s[1024];
  int t = threadIdx.x;
  int i = blockIdx.x * 1024 + t;
  int v = (i < N) ? cnt[i] : 0;
  s[t] = v;
  __syncthreads();
  for (int off = 1; off < 1024; off <<= 1) {
    int add = (t >= off) ? s[t - off] : 0;
    __syncthreads();
    s[t] += add;
    __syncthreads();
  }
  if (i < N) incl[i] = s[t];
  if (t == 1023) bsum[blockIdx.x] = s[1023];
}

__global__ void k_scan2(const int* __restrict__ bsum, int* __restrict__ bex, int nb) {
  if (threadIdx.x == 0) {
    int run = 0;
    for (int b = 0; b < nb; ++b) { bex[b] = run; run += bsum[b]; }
  }
}

__global__ void k_scan3(const int* __restrict__ incl, const int* __restrict__ cnt,
                        const int* __restrict__ bex, int* __restrict__ rowptr,
                        int* __restrict__ cursor, float* __restrict__ dis,
                        int N, int E) {
  int i = blockIdx.x * blockDim.x + threadIdx.x;
  if (i < N) {
    int c = cnt[i];
    int v = incl[i] - c + bex[i >> 10];
    rowptr[i] = v;
    cursor[i] = v;
    dis[i] = (c > 0) ? rsqrtf((float)c) : 0.0f;
  }
  if (i == 0) rowptr[N] = E;
}

// ---------- shortcut GEMM body: Sbf = bf16(x @ W_sc + b_sc) ----------
__device__ __forceinline__ void gemmsc_body(float* w_s, float* x_s, int bid,
                                            const float* __restrict__ X,
                                            const float* __restrict__ W,
                                            const float* __restrict__ bias,
                                            unsigned short* __restrict__ Sbf, int N) {
  for (int i4 = threadIdx.x; i4 < 1024; i4 += 512)
    *(float4*)&w_s[i4 * 4] = ((const float4*)W)[i4];
  int rowbase = bid * 128;
  for (int i4 = threadIdx.x; i4 < 2048; i4 += 512) {
    int r = i4 >> 4, c4 = i4 & 15;
    int row = rowbase + r;
    float4 v = (row < N) ? ntload4(X + (size_t)row * 64 + c4 * 4)
                         : make_float4(0.f, 0.f, 0.f, 0.f);
    *(float4*)&x_s[r * 64 + c4 * 4] = v;
  }
  __syncthreads();

  int lane = threadIdx.x & 63;
  int wid = threadIdx.x >> 6;
  int r0 = wid * 16;
  float bv = bias[lane];
  float acc[16];
#pragma unroll
  for (int r = 0; r < 16; ++r) acc[r] = bv;

  for (int d4 = 0; d4 < 16; ++d4) {
    float w0 = w_s[(d4 * 4 + 0) * 64 + lane];
    float w1 = w_s[(d4 * 4 + 1) * 64 + lane];
    float w2 = w_s[(d4 * 4 + 2) * 64 + lane];
    float w3 = w_s[(d4 * 4 + 3) * 64 + lane];
#pragma unroll
    for (int r = 0; r < 16; ++r) {
      float4 xv = *(const float4*)&x_s[(r0 + r) * 64 + d4 * 4];
      float a = acc[r];
      a = fmaf(xv.x, w0, a);
      a = fmaf(xv.y, w1, a);
      a = fmaf(xv.z, w2, a);
      a = fmaf(xv.w, w3, a);
      acc[r] = a;
    }
  }

#pragma unroll
  for (int r = 0; r < 16; ++r) {
    int row = rowbase + r0 + r;
    if (row < N)
      __builtin_nontemporal_store(f2bf(acc[r]), &Sbf[(size_t)row * 64 + lane]);
  }
}

// ---------- fused layer GEMM body ----------
// BNIN=false: input X fp32.  BNIN=true: input Xbf bf16; BN coefs computed
// in-block from sums/sumsq/g/be, + lrelu, applied during staging.
// Outputs: A02bf = bf16(X@W0+b - X@W2), Y1bf = bf16(X@W1), Y2bf = bf16(dis*X@W2)
template <bool BNIN>
__device__ __forceinline__ void gemm192_body(float* w_s, float* x_s, int bid,
                                             const float* __restrict__ X,
                                             const unsigned short* __restrict__ Xbf,
                                             const float* __restrict__ sums,
                                             const float* __restrict__ sumsq,
                                             const float* __restrict__ g,
                                             const float* __restrict__ be,
                                             const float* __restrict__ W,
                                             const float* __restrict__ bias,
                                             const float* __restrict__ dis,
                                             unsigned short* __restrict__ A02bf,
                                             unsigned short* __restrict__ Y1bf,
                                             unsigned short* __restrict__ Y2bf,
                                             int N) {
  __shared__ float sc_s[64], sh_s[64];
  // sc_s compute (64 threads) overlaps W staging (all threads) before sync1
  if (BNIN && threadIdx.x < 64) {
    int h = threadIdx.x;
    float inv_n = 1.0f / (float)N;
    float mu = sums[h] * inv_n;
    float var = sumsq[h] * inv_n - mu * mu;
    float sc = g[h] * rsqrtf(var + 1e-5f);
    sc_s[h] = sc;
    sh_s[h] = be[h] - mu * sc;
  }
  for (int i4 = threadIdx.x; i4 < 3072; i4 += 512) {
    int k = i4 >> 10, rem = i4 & 1023;
    int d = rem >> 4, h4 = rem & 15;
    float4 v = ((const float4*)W)[i4];
    *(float4*)&w_s[d * 192 + k * 64 + h4 * 4] = v;
  }
  if (BNIN) __syncthreads();
  int rowbase = bid * 128;
  for (int i4 = threadIdx.x; i4 < 2048; i4 += 512) {
    int r = i4 >> 4, c4 = i4 & 15;
    int row = rowbase + r;
    float4 v;
    if (BNIN) {
      if (row < N) {
        unsigned long long u = __builtin_nontemporal_load(
            (const unsigned long long*)(Xbf + (size_t)row * 64 + c4 * 4));
        v.x = bf2f((unsigned short)(u & 0xffffu));
        v.y = bf2f((unsigned short)((u >> 16) & 0xffffu));
        v.z = bf2f((unsigned short)((u >> 32) & 0xffffu));
        v.w = bf2f((unsigned short)(u >> 48));
      } else {
        v = make_float4(0.f, 0.f, 0.f, 0.f);
      }
      int cb = c4 * 4;
      float a = v.x * sc_s[cb + 0] + sh_s[cb + 0];
      float b = v.y * sc_s[cb + 1] + sh_s[cb + 1];
      float c = v.z * sc_s[cb + 2] + sh_s[cb + 2];
      float d = v.w * sc_s[cb + 3] + sh_s[cb + 3];
      v.x = (a > 0.f) ? a : 0.01f * a;
      v.y = (b > 0.f) ? b : 0.01f * b;
      v.z = (c > 0.f) ? c : 0.01f * c;
      v.w = (d > 0.f) ? d : 0.01f * d;
    } else {
      v = (row < N) ? ntload4(X + (size_t)row * 64 + c4 * 4)
                    : make_float4(0.f, 0.f, 0.f, 0.f);
    }
    *(float4*)&x_s[r * 64 + c4 * 4] = v;
  }
  __syncthreads();

  int lane = threadIdx.x & 63;
  int wid = threadIdx.x >> 6;
  int r0 = wid * 16;
  float bv = bias[lane];
  float acc[48];
#pragma unroll
  for (int r = 0; r < 16; ++r) {
    acc[r * 3 + 0] = bv;
    acc[r * 3 + 1] = 0.f;
    acc[r * 3 + 2] = 0.f;
  }

  for (int d4 = 0; d4 < 16; ++d4) {
    float w[12];
#pragma unroll
    for (int k = 0; k < 4; ++k)
#pragma unroll
      for (int j = 0; j < 3; ++j)
        w[k * 3 + j] = w_s[(d4 * 4 + k) * 192 + j * 64 + lane];
#pragma unroll
    for (int r = 0; r < 16; ++r) {
      float4 xv = *(const float4*)&x_s[(r0 + r) * 64 + d4 * 4];  // bcast
#pragma unroll
      for (int j = 0; j < 3; ++j) {
        float a = acc[r * 3 + j];
        a = fmaf(xv.x, w[0 * 3 + j], a);
        a = fmaf(xv.y, w[1 * 3 + j], a);
        a = fmaf(xv.z, w[2 * 3 + j], a);
        a = fmaf(xv.w, w[3 * 3 + j], a);
        acc[r * 3 + j] = a;
      }
    }
  }

#pragma unroll
  for (int r = 0; r < 16; ++r) {
    int row = rowbase + r0 + r;
    if (row < N) {
      size_t o = (size_t)row * 64 + lane;
      __builtin_nontemporal_store(f2bf(acc[r * 3 + 0] - acc[r * 3 + 2]), &A02bf[o]);
      __builtin_nontemporal_store(f2bf(acc[r * 3 + 1]), &Y1bf[o]);
      Y2bf[o] = f2bf(dis[row] * acc[r * 3 + 2]);  // gather source: keep cached
    }
  }
}

// ---------- fused A (role-interleaved): gemmsc | count | sentinel | poolinit -
__global__ __launch_bounds__(512) void k_fused_a(const float* __restrict__ X,
                                                 const float* __restrict__ W,
                                                 const float* __restrict__ bias,
                                                 unsigned short* __restrict__ Sbf,
                                                 const int* __restrict__ row,
                                                 int* __restrict__ cnt,
                                                 unsigned short* __restrict__ Y2bf,
                                                 unsigned short* __restrict__ Vbf,
                                                 unsigned* __restrict__ pooled,
                                                 int N, int E, int NBG, int NC,
                                                 int npool, int q) {
  __shared__ float w_s[64 * 64];
  __shared__ float x_s[128 * 64];
  int bid = blockIdx.x;
  bool isg = (bid % q == 0) && (bid / q < NBG);
  if (isg) {
    gemmsc_body(w_s, x_s, bid / q, X, W, bias, Sbf, N);
  } else {
    int before = min((bid + q - 1) / q, NBG);
    int oi = bid - before;
    if (oi < NC) {
      int e = oi * 512 + threadIdx.x;
      if (e < E) atomicAdd(&cnt[row[e]], 1);
    } else if (oi == NC) {
      if (threadIdx.x < 64) {
        Y2bf[(size_t)N * 64 + threadIdx.x] = 0;
        Vbf[(size_t)N * 64 + threadIdx.x] = 0;
      }
    } else {
      int i = (oi - NC - 1) * 512 + threadIdx.x;
      if (i < npool) pooled[i] = 0x007FFFFFu;  // key(-inf)
    }
  }
}

// ---------- fused B (role-interleaved): gemm192(l0) | fill ----------
__global__ __launch_bounds__(512) void k_fused_b(const float* __restrict__ X,
                                                 const float* __restrict__ W,
                                                 const float* __restrict__ bias,
                                                 const float* __restrict__ dis,
                                                 unsigned short* __restrict__ A02bf,
                                                 unsigned short* __restrict__ Y1bf,
                                                 unsigned short* __restrict__ Y2bf,
                                                 const int* __restrict__ row,
                                                 const int* __restrict__ col,
                                                 int* __restrict__ cursor,
                                                 int* __restrict__ ccol,
                                                 int N, int E, int NBG, int q) {
  __shared__ float w_s[64 * 192];
  __shared__ float x_s[128 * 64];
  int bid = blockIdx.x;
  bool isg = (bid % q == 0) && (bid / q < NBG);
  if (isg) {
    gemm192_body<false>(w_s, x_s, bid / q, X, nullptr, nullptr, nullptr, nullptr,
                        nullptr, W, bias, dis, A02bf, Y1bf, Y2bf, N);
  } else {
    int before = min((bid + q - 1) / q, NBG);
    int oi = bid - before;
    int e = oi * 512 + threadIdx.x;
    if (e < E) {
      int r = row[e];
      int idx = atomicAdd(&cursor[r], 1);
      __builtin_nontemporal_store(col[e], &ccol[idx]);
    }
  }
}

// ---------- layer GEMM (l>=1, standalone; Cbf input + in-block BN) ----------
__global__ __launch_bounds__(512) void k_gemm192(const unsigned short* __restrict__ Cbf,
                                                 const float* __restrict__ sums,
                                                 const float* __restrict__ sumsq,
                                                 const float* __restrict__ g,
                                                 const float* __restrict__ be,
                                                 const float* __restrict__ W,
                                                 const float* __restrict__ bias,
                                                 const float* __restrict__ dis,
                                                 unsigned short* __restrict__ A02bf,
                                                 unsigned short* __restrict__ Y1bf,
                                                 unsigned short* __restrict__ Y2bf,
                                                 int N) {
  __shared__ float w_s[64 * 192];
  __shared__ float x_s[128 * 64];
  gemm192_body<true>(w_s, x_s, blockIdx.x, nullptr, Cbf, sums, sumsq, g, be,
                     W, bias, dis, A02bf, Y1bf, Y2bf, N);
}

// ---------- prop v4 (R12 structure): row-per-wave persistent, 16-deep -------
// zbf PRE-SCALED: zbf[c] = bf16(dis[c]*z[c]);  (P z)[n] = -dis[n]*sum_c zbf[c]
// MODE 1: Vbf[n] = bf16( dis[n]*(bf2f(Y1bf[n]) - 2*dis[n]*acc) ); zeroes stats
// MODE 2: Cbf[n] = bf16( bf2f(A02bf[n]) - dis[n]*acc )  (+ fused BN stats fp32)
template <int MODE>
__global__ __launch_bounds__(256) void k_prop4(const int* __restrict__ rowptr,
                                               const int* __restrict__ ccol,
                                               const float* __restrict__ dis,
                                               const unsigned short* __restrict__ zbf,
                                               const unsigned short* __restrict__ inAbf,
                                               unsigned short* __restrict__ outbf,
                                               float* __restrict__ sums,
                                               float* __restrict__ sumsq,
                                               float* __restrict__ zstats,
                                               int N, int nwaves) {
  if (MODE == 1 && blockIdx.x == 0 && threadIdx.x < 128) zstats[threadIdx.x] = 0.f;
  int gw = blockIdx.x * 4 + (threadIdx.x >> 6);
  int lane = threadIdx.x & 63;
  int wid = threadIdx.x >> 6;
  float s_ = 0.f, s2_ = 0.f;
  for (int n = gw; n < N; n += nwaves) {
    int beg = rowptr[n], end = rowptr[n + 1];
    float acc = 0.f;
    for (int j = beg; j < end; j += 16) {
      int cc[16];
#pragma unroll
      for (int u = 0; u < 16; ++u) {
        int jj = j + u;
        int c = ccol[jj];            // allocation padded by 16 -> safe load
        cc[u] = (jj < end) ? c : N;  // row N is zeroed
      }
      float vv[16];
#pragma unroll
      for (int u = 0; u < 16; ++u) vv[u] = bf2f(zbf[(size_t)cc[u] * 64 + lane]);
#pragma unroll
      for (int u = 0; u < 16; ++u) acc += vv[u];
    }
    float dn = dis[n];
    size_t o = (size_t)n * 64 + lane;
    float av = bf2f(__builtin_nontemporal_load(&inAbf[o]));
    if (MODE == 1) {
      float V = av - 2.f * dn * acc;
      outbf[o] = f2bf(dn * V);  // gather source for prop_b: keep cached
    } else {
      float v = av - dn * acc;
      __builtin_nontemporal_store(f2bf(v), &outbf[o]);
      s_ += v;
      s2_ = fmaf(v, v, s2_);
    }
  }
  if (MODE == 2) {
    __shared__ float red[2][4][64];
    red[0][wid][lane] = s_;
    red[1][wid][lane] = s2_;
    __syncthreads();
    if (wid == 0) {
      float a = red[0][0][lane] + red[0][1][lane] + red[0][2][lane] + red[0][3][lane];
      float b = red[1][0][lane] + red[1][1][lane] + red[1][2][lane] + red[1][3][lane];
      atomicAdd(&sums[lane], a);
      atomicAdd(&sumsq[lane], b);
    }
  }
}

// fused: h = lrelu(bn(Cbf)) + Sbf; segment-max into pooled (coefs in-block)
__global__ void k_bnpool(const unsigned short* __restrict__ Cbf,
                         const float* __restrict__ sums, const float* __restrict__ sumsq,
                         const float* __restrict__ g, const float* __restrict__ be,
                         const unsigned short* __restrict__ Sbf,
                         const int* __restrict__ batch,
                         unsigned* __restrict__ pooled, int N) {
  __shared__ float sc_s[64], sh_s[64];
  if (threadIdx.x < 64) {
    int h = threadIdx.x;
    float inv_n = 1.0f / (float)N;
    float mu = sums[h] * inv_n;
    float var = sumsq[h] * inv_n - mu * mu;
    float sc = g[h] * rsqrtf(var + 1e-5f);
    sc_s[h] = sc;
    sh_s[h] = be[h] - mu * sc;
  }
  __syncthreads();
  int t = threadIdx.x;
  int h = t & 63;
  int rsub = t >> 6;
  int base = blockIdx.x * 64;
  float sc = sc_s[h], sh = sh_s[h];
  int cur_g = -1;
  unsigned best = 0;
  for (int i = 0; i < 16; ++i) {
    int n = base + rsub + 4 * i;
    if (n >= N) break;
    int gidx = batch[n];
    size_t o = (size_t)n * 64 + h;
    float a = bf2f(__builtin_nontemporal_load(&Cbf[o])) * sc + sh;
    a = (a > 0.f) ? a : 0.01f * a;
    a += bf2f(__builtin_nontemporal_load(&Sbf[o]));
    unsigned k = f2key(a);
    if (gidx != cur_g) {
      if (cur_g >= 0) atomicMax(&pooled[cur_g * 64 + h], best);
      cur_g = gidx;
      best = k;
    } else {
      best = max(best, k);
    }
  }
  if (cur_g >= 0) atomicMax(&pooled[cur_g * 64 + h], best);
}

__global__ void k_final(const unsigned* __restrict__ pooled, const float* __restrict__ w_lin,
                        const float* __restrict__ b_lin, float* __restrict__ out) {
  int g = blockIdx.x;
  int h = threadIdx.x;
  float v = key2f(pooled[g * 64 + h]) * w_lin[h];
  for (int off = 32; off > 0; off >>= 1) v += __shfl_down(v, off, 64);
  if (h == 0) out[g] = v + b_lin[0];
}

extern "C" void kernel_launch(void* const* d_in, const int* in_sizes, int n_in,
                              void* d_out, int out_size, void* d_ws, size_t ws_size,
                              hipStream_t stream) {
  const float* x = (const float*)d_in[0];
  const int* ei = (const int*)d_in[1];
  const int* batch = (const int*)d_in[2];
  const float* w1 = (const float*)d_in[3];
  const float* b1 = (const float*)d_in[4];
  const float* w2 = (const float*)d_in[5];
  const float* b2 = (const float*)d_in[6];
  const float* w3 = (const float*)d_in[7];
  const float* b3 = (const float*)d_in[8];
  const float* g1 = (const float*)d_in[9];
  const float* be1 = (const float*)d_in[10];
  const float* g2 = (const float*)d_in[11];
  const float* be2 = (const float*)d_in[12];
  const float* g3 = (const float*)d_in[13];
  const float* be3 = (const float*)d_in[14];
  const float* w_sc = (const float*)d_in[15];
  const float* b_sc = (const float*)d_in[16];
  const float* w_lin = (const float*)d_in[17];
  const float* b_lin = (const float*)d_in[18];

  int N = in_sizes[0] / 64;
  int E = in_sizes[1] / 2;
  int G = out_size;
  const int* row = ei;
  const int* col = ei + E;

  char* p = (char*)d_ws;
  auto carve = [&](size_t bytes) -> void* {
    void* r = (void*)p;
    p += (bytes + 255) & ~(size_t)255;
    return r;
  };
  int* cnt = (int*)carve((size_t)N * 4);
  float* dis = (float*)carve((size_t)N * 4);
  int* rowptr = (int*)carve((size_t)(N + 1) * 4);
  int* cursor = (int*)carve((size_t)N * 4);
  int* incl = (int*)carve((size_t)N * 4);
  int* bsum = (int*)carve(1024);
  int* bex = (int*)carve(1024);
  int* ccol = (int*)carve((size_t)(E + 64) * 4);   // +64 pad for batch over-read
  unsigned short* Sbf = (unsigned short*)carve((size_t)N * 64 * 2);
  unsigned short* A02bf = (unsigned short*)carve((size_t)N * 64 * 2);
  unsigned short* Y1bf = (unsigned short*)carve((size_t)N * 64 * 2);
  unsigned short* Y2bf = (unsigned short*)carve((size_t)(N + 1) * 64 * 2);  // row N = 0
  unsigned short* Vbf = (unsigned short*)carve((size_t)(N + 1) * 64 * 2);   // row N = 0
  unsigned short* Cbf = (unsigned short*)carve((size_t)N * 64 * 2);
  float* stats = (float*)carve(256 * 4);  // sums|sumsq
  unsigned* pooled = (unsigned*)carve((size_t)G * 64 * 4);

  int NBG = DIV_UP(N, 128);
  int NC = DIV_UP(E, 512);
  int npool = G * 64;
  int NPI = DIV_UP(npool, 512);

  // role-interleave strides (gemm blocks at bid % q == 0)
  int TA = NBG + NC + 1 + NPI;
  int qa = (NBG > 1) ? (TA - 1) / (NBG - 1) : 1;
  if (qa < 1) qa = 1;
  int TB = NBG + NC;
  int qb = (NBG > 1) ? (TB - 1) / (NBG - 1) : 1;
  if (qb < 1) qb = 1;

  // ---- graph build + overlapped independent compute ----
  hipMemsetAsync(cnt, 0, (size_t)N * 4, stream);
  // A: gemmsc || degree count || sentinel zero || poolinit (role-interleaved)
  k_fused_a<<<TA, 512, 0, stream>>>(x, w_sc, b_sc, Sbf, row, cnt,
                                    Y2bf, Vbf, pooled, N, E, NBG, NC, npool, qa);
  int nb = DIV_UP(N, 1024);
  k_scan1<<<nb, 1024, 0, stream>>>(cnt, incl, bsum, N);
  k_scan2<<<1, 64, 0, stream>>>(bsum, bex, nb);
  k_scan3<<<DIV_UP(N, 256), 256, 0, stream>>>(incl, cnt, bex, rowptr, cursor, dis, N, E);
  // B: gemm192(layer0) || CSR fill (role-interleaved)
  k_fused_b<<<TB, 512, 0, stream>>>(x, w1, b1, dis, A02bf, Y1bf, Y2bf,
                                    row, col, cursor, ccol, N, E, NBG, qb);

  const float* Ws[3] = {w1, w2, w3};
  const float* bs[3] = {b1, b2, b3};
  const float* gs[3] = {g1, g2, g3};
  const float* bes[3] = {be1, be2, be3};

  const int PBLK = 2048;      // persistent blocks, 4 waves each (all resident)
  const int NWAVE = PBLK * 4;
  for (int l = 0; l < 3; ++l) {
    if (l > 0)
      k_gemm192<<<NBG, 512, 0, stream>>>(Cbf, stats, stats + 64, gs[l - 1], bes[l - 1],
                                         Ws[l], bs[l], dis, A02bf, Y1bf, Y2bf, N);
    // Vbf = bf16( dis * (Y1 + 2*P*Y2) )   (also zeroes stats)
    k_prop4<1><<<PBLK, 256, 0, stream>>>(rowptr, ccol, dis, Y2bf, Y1bf,
                                         Vbf, nullptr, nullptr, stats, N, NWAVE);
    // Cbf = bf16( (Y0 - Y2) + P*V )  (+ fused BN stats)
    k_prop4<2><<<PBLK, 256, 0, stream>>>(rowptr, ccol, dis, Vbf, A02bf,
                                         Cbf, stats, stats + 64, nullptr, N, NWAVE);
  }

  k_bnpool<<<DIV_UP(N, 64), 256, 0, stream>>>(Cbf, stats, stats + 64, g3, be3,
                                              Sbf, batch, pooled, N);
  k_final<<<G, 64, 0, stream>>>(pooled, w_lin, b_lin, (float*)d_out);
}